// Round 8
// baseline (303.089 us; speedup 1.0000x reference)
//
#include <hip/hip_runtime.h>
#include <hip/hip_bf16.h>

#define BB 8
#define SQ 2048
#define SK 2048
#define DD 128
#define INV_TEMPER 0.08838834764831845f  // 1/sqrt(128)

using s16x8 = __attribute__((ext_vector_type(8))) short;
using f32x4 = __attribute__((ext_vector_type(4))) float;

__device__ __forceinline__ unsigned short f2bf(float f) {
  union { float f; unsigned u; } v; v.f = f;
  unsigned r = v.u + 0x7FFFu + ((v.u >> 16) & 1u);
  return (unsigned short)(r >> 16);
}
__device__ __forceinline__ float bf2f(unsigned short h) {
  union { unsigned u; float f; } v; v.u = ((unsigned)h) << 16; return v.f;
}

// K fp32 -> bf16, same layout [b][k][d]
__global__ __launch_bounds__(256) void prep_k_kernel(const float* __restrict__ k,
                                                     unsigned short* __restrict__ kb) {
  const size_t i = ((size_t)blockIdx.x * 256 + threadIdx.x) * 8;
  const float4 a = *(const float4*)(k + i);
  const float4 c = *(const float4*)(k + i + 4);
  ushort4 o0, o1;
  o0.x = f2bf(a.x); o0.y = f2bf(a.y); o0.z = f2bf(a.z); o0.w = f2bf(a.w);
  o1.x = f2bf(c.x); o1.y = f2bf(c.y); o1.z = f2bf(c.z); o1.w = f2bf(c.w);
  *(ushort4*)(kb + i) = o0;
  *(ushort4*)(kb + i + 4) = o1;
}

// V fp32 [b][k][d] -> bf16 V^T [b][d][k]
__global__ __launch_bounds__(256) void prep_v_kernel(const float* __restrict__ v,
                                                     unsigned short* __restrict__ vt) {
  constexpr int TS = 132;
  __shared__ __align__(16) unsigned short tile[64 * TS];
  const int tid = threadIdx.x;
  const int bid = blockIdx.x;
  const int b  = bid >> 5;
  const int k0 = (bid & 31) << 6;
#pragma unroll
  for (int p = 0; p < 8; ++p) {
    const int row = p * 8 + (tid >> 5);
    const int c4  = (tid & 31) << 2;
    const float4 vv = *(const float4*)(v + ((size_t)(b * SK + k0 + row)) * DD + c4);
    ushort4 o; o.x = f2bf(vv.x); o.y = f2bf(vv.y); o.z = f2bf(vv.z); o.w = f2bf(vv.w);
    *(ushort4*)(&tile[row * TS + c4]) = o;
  }
  __syncthreads();
#pragma unroll
  for (int p = 0; p < 8; ++p) {
    const int u = p * 256 + tid;
    const int d  = u >> 4;
    const int kw = (u & 15) << 2;
    ushort4 o;
    o.x = tile[(kw + 0) * TS + d];
    o.y = tile[(kw + 1) * TS + d];
    o.z = tile[(kw + 2) * TS + d];
    o.w = tile[(kw + 3) * TS + d];
    *(ushort4*)(vt + ((size_t)(b * DD + d)) * SK + k0 + kw) = o;
  }
}

// mask int32 -> 1 bit/elem via ballot. One wave = one row (2048 ints -> 32 u64).
__global__ __launch_bounds__(256) void maskpack(const int* __restrict__ m,
                                                unsigned long long* __restrict__ mb) {
  const int gw = (blockIdx.x * 256 + threadIdx.x) >> 6;  // global row
  const int lane = threadIdx.x & 63;
  const int* rp = m + (size_t)gw * SK;
  unsigned long long* wp = mb + (size_t)gw * (SK / 64);
#pragma unroll 4
  for (int i = 0; i < 32; ++i) {
    const int mv = __builtin_nontemporal_load(rp + i * 64 + lane);
    const unsigned long long bal = __ballot(mv != 0);
    if (lane == 0) wp[i] = bal;
  }
}

// Single-pass fused attention. Block = 32 q-rows, 8 waves; wave owns a private
// 256-k slice. E = exp(s) kept packed-bf16 in 64 VGPRs (fully unrolled, static
// indexing). One barrier to reduce l; emit phase (p=E*il -> LDS bounce -> attn
// NT stores + PV MFMA) is barrier-free (intra-wave lgkmcnt only).
#define BMSR 264  // bm row stride bytes
#define PWS  36   // per-wave p tile row stride (ushorts)

__global__ __launch_bounds__(512, 2) void fused_attn(
    const float* __restrict__ q, const unsigned long long* __restrict__ mb,
    const unsigned short* __restrict__ kb, const unsigned short* __restrict__ vt,
    float* __restrict__ outp, float* __restrict__ attn) {
  __shared__ unsigned char bm[32 * BMSR];                  //  8,448 B
  __shared__ __align__(16) unsigned short p_w[8][32][PWS]; // 18,432 B
  __shared__ float obuf[32 * 128];                         // 16,384 B
  __shared__ float redl[8][32];                            //  1,024 B
  __shared__ float il_s[32];                               //    128 B

  const int tid = threadIdx.x;
  const int bid = blockIdx.x;
  // 512 blocks = 8 XCD x 64 (bijective): batch pinned to one XCD, kb/vt L2-hot
  const int swz = ((bid & 7) << 6) + (bid >> 3);
  const int b  = swz >> 6;
  const int q0 = (swz & 63) << 5;
  const int lane = tid & 63;
  const int w    = tid >> 6;       // wave 0..7
  const int lrow = lane & 15;
  const int lk   = lane >> 4;
  const int rowb = lk << 2;
  const int slice0 = w << 8;       // this wave's 256-k slice

  // zero O accumulator buffer
#pragma unroll
  for (int i = 0; i < 8; ++i) obuf[tid + (i << 9)] = 0.0f;

  // stage mask bits: 32 rows x 32 u64 words (1024 words, 512 threads x 2)
  {
    const unsigned long long* src = mb + (size_t)(b * SQ + q0) * (SK / 64);
#pragma unroll
    for (int i = 0; i < 2; ++i) {
      const int u = (i << 9) + tid;
      const int row = u >> 5, wd = u & 31;
      *(unsigned long long*)&bm[row * BMSR + (wd << 3)] = src[row * 32 + wd];
    }
  }

  // Q A-fragments (32 rows x 128 d)
  s16x8 af0[4], af1[4];
#pragma unroll
  for (int ks = 0; ks < 4; ++ks) {
    const float* qp0 = q + ((size_t)(b * SQ + q0 + lrow)) * DD + ks * 32 + lk * 8;
    const float* qp1 = qp0 + 16 * DD;
    const float4 a0 = *(const float4*)qp0;
    const float4 a1 = *(const float4*)(qp0 + 4);
    const float4 c0 = *(const float4*)qp1;
    const float4 c1 = *(const float4*)(qp1 + 4);
    s16x8 x, y;
    x[0] = (short)f2bf(a0.x); x[1] = (short)f2bf(a0.y); x[2] = (short)f2bf(a0.z); x[3] = (short)f2bf(a0.w);
    x[4] = (short)f2bf(a1.x); x[5] = (short)f2bf(a1.y); x[6] = (short)f2bf(a1.z); x[7] = (short)f2bf(a1.w);
    y[0] = (short)f2bf(c0.x); y[1] = (short)f2bf(c0.y); y[2] = (short)f2bf(c0.z); y[3] = (short)f2bf(c0.w);
    y[4] = (short)f2bf(c1.x); y[5] = (short)f2bf(c1.y); y[6] = (short)f2bf(c1.z); y[7] = (short)f2bf(c1.w);
    af0[ks] = x; af1[ks] = y;
  }

  __syncthreads();  // bm + obuf ready

  const unsigned short* kfp = kb + (size_t)b * SK * DD + (size_t)(slice0 + lrow) * DD + lk * 8;

  float ls[8];
#pragma unroll
  for (int i = 0; i < 8; ++i) ls[i] = 0.0f;
  unsigned E32[64];  // 16 tiles x 2 rt x 2 pairs, packed bf16 (static idx only)

  // ---- main loop: QK^T -> e = exp(s) -> E regs + lsum. No barriers, no LDS writes.
#pragma unroll
  for (int ct = 0; ct < 16; ++ct) {
    s16x8 kf[4];
#pragma unroll
    for (int ks = 0; ks < 4; ++ks)
      kf[ks] = *(const s16x8*)(kfp + (size_t)(ct << 4) * DD + ks * 32);
    f32x4 a0 = {0.f,0.f,0.f,0.f}, a1 = {0.f,0.f,0.f,0.f};
    __builtin_amdgcn_s_setprio(1);
#pragma unroll
    for (int ks = 0; ks < 4; ++ks) {
      a0 = __builtin_amdgcn_mfma_f32_16x16x32_bf16(af0[ks], kf[ks], a0, 0, 0, 0);
      a1 = __builtin_amdgcn_mfma_f32_16x16x32_bf16(af1[ks], kf[ks], a1, 0, 0, 0);
    }
    __builtin_amdgcn_s_setprio(0);
    const int colg = slice0 + (ct << 4) + lrow;
    const int byb = colg >> 3, bit = colg & 7;
#pragma unroll
    for (int rt = 0; rt < 2; ++rt) {
      float e[4];
#pragma unroll
      for (int r = 0; r < 4; ++r) {
        const int row = rt * 16 + rowb + r;
        const int live = (bm[row * BMSR + byb] >> bit) & 1;
        const float s = (rt ? a1[r] : a0[r]) * INV_TEMPER;
        e[r] = live ? __expf(s) : 0.0f;
        ls[rt * 4 + r] += e[r];
      }
      E32[ct * 4 + rt * 2 + 0] = (unsigned)f2bf(e[0]) | ((unsigned)f2bf(e[1]) << 16);
      E32[ct * 4 + rt * 2 + 1] = (unsigned)f2bf(e[2]) | ((unsigned)f2bf(e[3]) << 16);
    }
  }

  // ---- l reduce: 16-lane shfl (cols of this wave's slice) + cross-wave LDS ----
#pragma unroll
  for (int i = 0; i < 8; ++i) {
    float l = ls[i];
#pragma unroll
    for (int d = 1; d < 16; d <<= 1) l += __shfl_xor(l, d);
    ls[i] = l;
  }
  if (lrow == 0) {
#pragma unroll
    for (int i = 0; i < 8; ++i)
      redl[w][((i >> 2) << 4) + rowb + (i & 3)] = ls[i];
  }
  __syncthreads();
  if (tid < 32) {
    float l = 0.f;
#pragma unroll
    for (int ww = 0; ww < 8; ++ww) l += redl[ww][tid];
    il_s[tid] = 1.0f / l;
  }
  __syncthreads();
  float il[8];
#pragma unroll
  for (int i = 0; i < 8; ++i)
    il[i] = il_s[((i >> 2) << 4) + rowb + (i & 3)];

  // ---- emit: per 32-k chunk: p = E*il -> p_w (intra-wave) -> attn NT + PV ----
  f32x4 o[2][8];
#pragma unroll
  for (int rt = 0; rt < 2; ++rt)
#pragma unroll
    for (int nt = 0; nt < 8; ++nt) o[rt][nt] = f32x4{0.f,0.f,0.f,0.f};

  const unsigned short* vfp = vt + ((size_t)(b * DD + lrow)) * SK + slice0 + lk * 8;
  const int arow = lane >> 1;
  const int kh   = lane & 1;
  float* abase = attn + ((size_t)(b * SQ + q0 + arow)) * SK + slice0 + (kh << 4);

#pragma unroll
  for (int c = 0; c < 8; ++c) {
    // V-frags (consumed at chunk end; latency hides under p bounce + cvt)
    s16x8 vf[8];
#pragma unroll
    for (int nt = 0; nt < 8; ++nt)
      vf[nt] = *(const s16x8*)(vfp + (size_t)(nt << 4) * SK + (c << 5));
    // p = E * il -> per-wave LDS tile [32 rows][32 k]
#pragma unroll
    for (int t2 = 0; t2 < 2; ++t2) {
      const int t = (c << 1) + t2;
#pragma unroll
      for (int rt = 0; rt < 2; ++rt)
#pragma unroll
        for (int pr = 0; pr < 2; ++pr) {
          const unsigned pk = E32[t * 4 + rt * 2 + pr];
          const int r0 = rt * 16 + rowb + (pr << 1);
          p_w[w][r0    ][(t2 << 4) + lrow] = f2bf(bf2f((unsigned short)(pk & 0xffff)) * il[rt * 4 + (pr << 1)]);
          p_w[w][r0 + 1][(t2 << 4) + lrow] = f2bf(bf2f((unsigned short)(pk >> 16))    * il[rt * 4 + (pr << 1) + 1]);
        }
    }
    asm volatile("s_waitcnt lgkmcnt(0)" ::: "memory");
    __builtin_amdgcn_sched_barrier(0);
    // A-frags for PV
    const s16x8 pa0 = *(const s16x8*)(&p_w[w][lrow][lk << 3]);
    const s16x8 pa1 = *(const s16x8*)(&p_w[w][16 + lrow][lk << 3]);
    // attn NT stores: lane covers 16 cols of one row (64B); 2 lanes = 128B run
    {
      const s16x8 p0 = *(const s16x8*)(&p_w[w][arow][kh << 4]);
      const s16x8 p1 = *(const s16x8*)(&p_w[w][arow][(kh << 4) + 8]);
      f32x4 g0, g1, g2, g3;
#pragma unroll
      for (int j = 0; j < 4; ++j) {
        g0[j] = bf2f((unsigned short)p0[j]);
        g1[j] = bf2f((unsigned short)p0[4 + j]);
        g2[j] = bf2f((unsigned short)p1[j]);
        g3[j] = bf2f((unsigned short)p1[4 + j]);
      }
      float* ap = abase + (c << 5);
      __builtin_nontemporal_store(g0, (f32x4*)ap);
      __builtin_nontemporal_store(g1, (f32x4*)(ap + 4));
      __builtin_nontemporal_store(g2, (f32x4*)(ap + 8));
      __builtin_nontemporal_store(g3, (f32x4*)(ap + 12));
    }
    // PV MFMA (p normalized -> O comes out normalized)
    __builtin_amdgcn_s_setprio(1);
#pragma unroll
    for (int nt = 0; nt < 8; ++nt) {
      o[0][nt] = __builtin_amdgcn_mfma_f32_16x16x32_bf16(pa0, vf[nt], o[0][nt], 0, 0, 0);
      o[1][nt] = __builtin_amdgcn_mfma_f32_16x16x32_bf16(pa1, vf[nt], o[1][nt], 0, 0, 0);
    }
    __builtin_amdgcn_s_setprio(0);
  }

  // ---- cross-wave O reduce (k-slice partials) + out ----
  __syncthreads();  // all p_w traffic done; obuf safe to accumulate
#pragma unroll
  for (int rt = 0; rt < 2; ++rt)
#pragma unroll
    for (int nt = 0; nt < 8; ++nt)
#pragma unroll
      for (int r = 0; r < 4; ++r)
        atomicAdd(&obuf[(rt * 16 + rowb + r) * 128 + (nt << 4) + lrow], o[rt][nt][r]);
  __syncthreads();

  {
    const int orow = tid >> 4;
    const int ocol = (tid & 15) << 3;
    const float* ob = &obuf[orow * 128 + ocol];
    float4 u0, u1;
    u0.x = ob[0]; u0.y = ob[1]; u0.z = ob[2]; u0.w = ob[3];
    u1.x = ob[4]; u1.y = ob[5]; u1.z = ob[6]; u1.w = ob[7];
    float* op = outp + ((size_t)(b * SQ + q0 + orow)) * DD + ocol;
    *(float4*)op = u0;
    *(float4*)(op + 4) = u1;
  }
}

extern "C" void kernel_launch(void* const* d_in, const int* in_sizes, int n_in,
                              void* d_out, int out_size, void* d_ws, size_t ws_size,
                              hipStream_t stream) {
  const float* q = (const float*)d_in[0];
  const float* k = (const float*)d_in[1];
  const float* v = (const float*)d_in[2];
  const int* mask = (const int*)d_in[3];
  float* outp = (float*)d_out;
  float* attn = outp + (size_t)BB * SQ * DD;

  unsigned short* kb = (unsigned short*)d_ws;                       // 4.2 MB
  unsigned short* vt = kb + (size_t)BB * SK * DD;                   // 4.2 MB
  unsigned long long* mbits = (unsigned long long*)(vt + (size_t)BB * SK * DD);  // 4.2 MB

  prep_k_kernel<<<(BB * SK * DD) / (256 * 8), 256, 0, stream>>>(k, kb);
  prep_v_kernel<<<BB * (SK / 64), 256, 0, stream>>>(v, vt);
  maskpack<<<(BB * SQ) / 4, 256, 0, stream>>>(mask, mbits);
  fused_attn<<<BB * (SQ / 32), 512, 0, stream>>>(q, mbits, kb, vt, outp, attn);
}

// Round 9
// 278.583 us; speedup vs baseline: 1.0880x; 1.0880x over previous
//
#include <hip/hip_runtime.h>
#include <hip/hip_bf16.h>

#define BB 8
#define SQ 2048
#define SK 2048
#define DD 128
#define INV_TEMPER 0.08838834764831845f  // 1/sqrt(128)

using s16x8 = __attribute__((ext_vector_type(8))) short;
using f32x4 = __attribute__((ext_vector_type(4))) float;

__device__ __forceinline__ unsigned short f2bf(float f) {
  union { float f; unsigned u; } v; v.f = f;
  unsigned r = v.u + 0x7FFFu + ((v.u >> 16) & 1u);
  return (unsigned short)(r >> 16);
}
__device__ __forceinline__ float bf2f(unsigned short h) {
  union { unsigned u; float f; } v; v.u = ((unsigned)h) << 16; return v.f;
}

// K fp32 -> bf16, same layout [b][k][d]
__global__ __launch_bounds__(256) void prep_k_kernel(const float* __restrict__ k,
                                                     unsigned short* __restrict__ kb) {
  const size_t i = ((size_t)blockIdx.x * 256 + threadIdx.x) * 8;
  const float4 a = *(const float4*)(k + i);
  const float4 c = *(const float4*)(k + i + 4);
  ushort4 o0, o1;
  o0.x = f2bf(a.x); o0.y = f2bf(a.y); o0.z = f2bf(a.z); o0.w = f2bf(a.w);
  o1.x = f2bf(c.x); o1.y = f2bf(c.y); o1.z = f2bf(c.z); o1.w = f2bf(c.w);
  *(ushort4*)(kb + i) = o0;
  *(ushort4*)(kb + i + 4) = o1;
}

// V fp32 [b][k][d] -> bf16 V^T [b][d][k]
__global__ __launch_bounds__(256) void prep_v_kernel(const float* __restrict__ v,
                                                     unsigned short* __restrict__ vt) {
  constexpr int TS = 132;
  __shared__ __align__(16) unsigned short tile[64 * TS];
  const int tid = threadIdx.x;
  const int bid = blockIdx.x;
  const int b  = bid >> 5;
  const int k0 = (bid & 31) << 6;
#pragma unroll
  for (int p = 0; p < 8; ++p) {
    const int row = p * 8 + (tid >> 5);
    const int c4  = (tid & 31) << 2;
    const float4 vv = *(const float4*)(v + ((size_t)(b * SK + k0 + row)) * DD + c4);
    ushort4 o; o.x = f2bf(vv.x); o.y = f2bf(vv.y); o.z = f2bf(vv.z); o.w = f2bf(vv.w);
    *(ushort4*)(&tile[row * TS + c4]) = o;
  }
  __syncthreads();
#pragma unroll
  for (int p = 0; p < 8; ++p) {
    const int u = p * 256 + tid;
    const int d  = u >> 4;
    const int kw = (u & 15) << 2;
    ushort4 o;
    o.x = tile[(kw + 0) * TS + d];
    o.y = tile[(kw + 1) * TS + d];
    o.z = tile[(kw + 2) * TS + d];
    o.w = tile[(kw + 3) * TS + d];
    *(ushort4*)(vt + ((size_t)(b * DD + d)) * SK + k0 + kw) = o;
  }
}

// mask int32 -> 1 bit/elem via ballot. One wave = one row.
__global__ __launch_bounds__(256) void maskpack(const int* __restrict__ m,
                                                unsigned long long* __restrict__ mb) {
  const int gw = (blockIdx.x * 256 + threadIdx.x) >> 6;
  const int lane = threadIdx.x & 63;
  const int* rp = m + (size_t)gw * SK;
  unsigned long long* wp = mb + (size_t)gw * (SK / 64);
#pragma unroll 4
  for (int i = 0; i < 32; ++i) {
    const int mv = __builtin_nontemporal_load(rp + i * 64 + lane);
    const unsigned long long bal = __ballot(mv != 0);
    if (lane == 0) wp[i] = bal;
  }
}

// Fused attention, 2-pass recompute, wave-decoupled.
// Block = 256 thr / 4 waves / 16 q-rows. Wave w owns k-slice [w*512,(w+1)*512):
// pass1 QK->sum(exp) over slice (no barriers), one block-reduce for l, pass2
// QK recompute -> p=exp*il -> private p_w bounce (lgkm only) -> plain coalesced
// attn stores + PV partials; one final LDS-atomic merge for O.
#define BMSR 264  // mask-bit row stride (bytes): 256 data + 8 pad
#define PWS  40   // p_w row stride (ushorts): 80 B, 16B-aligned rows

__global__ __launch_bounds__(256, 2) void fused_attn(
    const float* __restrict__ q, const unsigned long long* __restrict__ mb,
    const unsigned short* __restrict__ kb, const unsigned short* __restrict__ vt,
    float* __restrict__ outp, float* __restrict__ attn) {
  __shared__ unsigned char bm[16 * BMSR];                  //  4,224 B
  __shared__ __align__(16) unsigned short p_w[4][16][PWS]; //  5,120 B
  __shared__ float obuf[16 * 128];                         //  8,192 B
  __shared__ float redl[4][16];                            //    256 B
  __shared__ float il_s[16];                               //     64 B

  const int tid = threadIdx.x;
  const int bid = blockIdx.x;
  // 1024 blocks = 8 XCD x 128 (bijective): batch pinned to one XCD
  const int swz = ((bid & 7) << 7) + (bid >> 3);
  const int b  = swz >> 7;
  const int q0 = (swz & 127) << 4;   // 16 q-rows
  const int lane = tid & 63;
  const int w    = tid >> 6;         // wave 0..3
  const int lrow = lane & 15;
  const int lk   = lane >> 4;
  const int rowb = lk << 2;
  const int slice0 = w << 9;         // wave's 512-k slice

  // zero O accumulator
#pragma unroll
  for (int i = 0; i < 8; ++i) obuf[tid + (i << 8)] = 0.0f;

  // stage mask bits: 16 rows x 32 u64 = 512 words; 256 thr x 2
  {
    const unsigned long long* src = mb + (size_t)(b * SQ + q0) * (SK / 64);
#pragma unroll
    for (int i = 0; i < 2; ++i) {
      const int u = (i << 8) + tid;
      const int row = u >> 5, wd = u & 31;
      *(unsigned long long*)&bm[row * BMSR + (wd << 3)] = src[row * 32 + wd];
    }
  }

  // Q A-fragments (16 rows x 128 d)
  s16x8 af[4];
#pragma unroll
  for (int ks = 0; ks < 4; ++ks) {
    const float* qp = q + ((size_t)(b * SQ + q0 + lrow)) * DD + ks * 32 + lk * 8;
    const float4 a0 = *(const float4*)qp;
    const float4 a1 = *(const float4*)(qp + 4);
    s16x8 x;
    x[0] = (short)f2bf(a0.x); x[1] = (short)f2bf(a0.y); x[2] = (short)f2bf(a0.z); x[3] = (short)f2bf(a0.w);
    x[4] = (short)f2bf(a1.x); x[5] = (short)f2bf(a1.y); x[6] = (short)f2bf(a1.z); x[7] = (short)f2bf(a1.w);
    af[ks] = x;
  }

  const unsigned short* kfp = kb + (size_t)b * SK * DD + (size_t)(slice0 + lrow) * DD + lk * 8;

  __syncthreads();  // bm ready

  // ---- pass 1: l[row] = sum_k exp(s) over this wave's slice (no barriers) ----
  float ls[4];
#pragma unroll
  for (int r = 0; r < 4; ++r) ls[r] = 0.0f;

  auto qk = [&](const s16x8* kf) {
    f32x4 a = {0.f, 0.f, 0.f, 0.f};
    __builtin_amdgcn_s_setprio(1);
#pragma unroll
    for (int ks = 0; ks < 4; ++ks)
      a = __builtin_amdgcn_mfma_f32_16x16x32_bf16(af[ks], kf[ks], a, 0, 0, 0);
    __builtin_amdgcn_s_setprio(0);
    return a;
  };
  auto sink1 = [&](int ct, const f32x4& a) {
    const int colg = slice0 + (ct << 4) + lrow;
    const int byb = colg >> 3, bit = colg & 7;
#pragma unroll
    for (int r = 0; r < 4; ++r) {
      const int live = (bm[(rowb + r) * BMSR + byb] >> bit) & 1;
      const float s = a[r] * INV_TEMPER;
      ls[r] += live ? __expf(s) : 0.0f;
    }
  };

  s16x8 kA[4], kB[4];
#pragma unroll
  for (int ks = 0; ks < 4; ++ks) kA[ks] = *(const s16x8*)(kfp + ks * 32);  // ct=0

#pragma unroll 1
  for (int tp = 0; tp < 16; ++tp) {
    const int t0 = tp << 1;
#pragma unroll
    for (int ks = 0; ks < 4; ++ks)
      kB[ks] = *(const s16x8*)(kfp + (size_t)((t0 + 1) << 4) * DD + ks * 32);
    sink1(t0, qk(kA));
#pragma unroll
    for (int ks = 0; ks < 4; ++ks)
      kA[ks] = *(const s16x8*)(kfp + (size_t)(((t0 + 2) & 31) << 4) * DD + ks * 32);
    sink1(t0 + 1, qk(kB));
  }

  // ---- l reduce: shfl over 16-lane col group + cross-wave via LDS ----
#pragma unroll
  for (int r = 0; r < 4; ++r) {
    float l = ls[r];
#pragma unroll
    for (int d = 1; d < 16; d <<= 1) l += __shfl_xor(l, d);
    ls[r] = l;
  }
  if (lrow == 0) {
#pragma unroll
    for (int r = 0; r < 4; ++r) redl[w][rowb + r] = ls[r];
  }
  __syncthreads();
  if (tid < 16)
    il_s[tid] = 1.0f / (redl[0][tid] + redl[1][tid] + redl[2][tid] + redl[3][tid]);
  __syncthreads();
  float il[4];
#pragma unroll
  for (int r = 0; r < 4; ++r) il[r] = il_s[rowb + r];

  // ---- pass 2: recompute QK -> p -> p_w (private) -> attn (plain, coalesced) + PV ----
  f32x4 o[8];
#pragma unroll
  for (int nt = 0; nt < 8; ++nt) o[nt] = f32x4{0.f, 0.f, 0.f, 0.f};

  const int arow = lane >> 2;          // 0..15
  const int ac   = (lane & 3) << 3;    // 0,8,16,24
  float* abase = attn + ((size_t)(b * SQ + q0 + arow)) * SK + slice0 + ac;

#pragma unroll 1
  for (int c = 0; c < 16; ++c) {
    // K frags for the 2 QK tiles of this 32-col chunk (issued first)
    s16x8 kf[8];
#pragma unroll
    for (int t2 = 0; t2 < 2; ++t2)
#pragma unroll
      for (int ks = 0; ks < 4; ++ks)
        kf[t2 * 4 + ks] = *(const s16x8*)(kfp + (size_t)(((c << 1) + t2) << 4) * DD + ks * 32);
    // V frags (consumed last; latency hides under QK+sink)
    s16x8 vf[8];
#pragma unroll
    for (int nt = 0; nt < 8; ++nt)
      vf[nt] = *(const s16x8*)(vt + ((size_t)(b * DD + (nt << 4) + lrow)) * SK + slice0 + (c << 5) + lk * 8);

    f32x4 a0 = qk(&kf[0]);
    f32x4 a1 = qk(&kf[4]);
    // p = exp(s)*il -> private p_w tile [16 rows][32 cols]
#pragma unroll
    for (int t2 = 0; t2 < 2; ++t2) {
      const f32x4& a = t2 ? a1 : a0;
      const int colg = slice0 + (c << 5) + (t2 << 4) + lrow;
      const int byb = colg >> 3, bit = colg & 7;
#pragma unroll
      for (int r = 0; r < 4; ++r) {
        const int live = (bm[(rowb + r) * BMSR + byb] >> bit) & 1;
        const float s = a[r] * INV_TEMPER;
        const float p = live ? __expf(s) * il[r] : 0.0f;
        p_w[w][rowb + r][(t2 << 4) + lrow] = f2bf(p);
      }
    }
    asm volatile("s_waitcnt lgkmcnt(0)" ::: "memory");
    __builtin_amdgcn_sched_barrier(0);
    // PV A-frag (own wave's tile; intra-wave dependency only)
    const s16x8 pa = *(const s16x8*)(&p_w[w][lrow][lk << 3]);
    // attn store: plain float4; 4 lanes cover 128B contiguous per row
    {
      const s16x8 pr = *(const s16x8*)(&p_w[w][arow][ac]);
      float4 g0, g1;
      g0.x = bf2f((unsigned short)pr[0]); g0.y = bf2f((unsigned short)pr[1]);
      g0.z = bf2f((unsigned short)pr[2]); g0.w = bf2f((unsigned short)pr[3]);
      g1.x = bf2f((unsigned short)pr[4]); g1.y = bf2f((unsigned short)pr[5]);
      g1.z = bf2f((unsigned short)pr[6]); g1.w = bf2f((unsigned short)pr[7]);
      float* ap = abase + (c << 5);
      *(float4*)ap = g0;
      *(float4*)(ap + 4) = g1;
    }
    // PV MFMA (p normalized -> O normalized)
    __builtin_amdgcn_s_setprio(1);
#pragma unroll
    for (int nt = 0; nt < 8; ++nt)
      o[nt] = __builtin_amdgcn_mfma_f32_16x16x32_bf16(pa, vf[nt], o[nt], 0, 0, 0);
    __builtin_amdgcn_s_setprio(0);
  }

  // ---- merge wave partials (k-slices) and write out ----
  __syncthreads();
#pragma unroll
  for (int nt = 0; nt < 8; ++nt)
#pragma unroll
    for (int r = 0; r < 4; ++r)
      atomicAdd(&obuf[(rowb + r) * 128 + (nt << 4) + lrow], o[nt][r]);
  __syncthreads();

  {
    const int orow = tid >> 4;          // 0..15
    const int ocol = (tid & 15) << 3;   // 0..120
    const float* ob = &obuf[orow * 128 + ocol];
    float4 u0, u1;
    u0.x = ob[0]; u0.y = ob[1]; u0.z = ob[2]; u0.w = ob[3];
    u1.x = ob[4]; u1.y = ob[5]; u1.z = ob[6]; u1.w = ob[7];
    float* op = outp + ((size_t)(b * SQ + q0 + orow)) * DD + ocol;
    *(float4*)op = u0;
    *(float4*)(op + 4) = u1;
  }
}

extern "C" void kernel_launch(void* const* d_in, const int* in_sizes, int n_in,
                              void* d_out, int out_size, void* d_ws, size_t ws_size,
                              hipStream_t stream) {
  const float* q = (const float*)d_in[0];
  const float* k = (const float*)d_in[1];
  const float* v = (const float*)d_in[2];
  const int* mask = (const int*)d_in[3];
  float* outp = (float*)d_out;
  float* attn = outp + (size_t)BB * SQ * DD;

  unsigned short* kb = (unsigned short*)d_ws;                       // 4.2 MB
  unsigned short* vt = kb + (size_t)BB * SK * DD;                   // 4.2 MB
  unsigned long long* mbits = (unsigned long long*)(vt + (size_t)BB * SK * DD);  // 4.2 MB

  prep_k_kernel<<<(BB * SK * DD) / (256 * 8), 256, 0, stream>>>(k, kb);
  prep_v_kernel<<<BB * (SK / 64), 256, 0, stream>>>(v, vt);
  maskpack<<<(BB * SQ) / 4, 256, 0, stream>>>(mask, mbits);
  fused_attn<<<BB * (SQ / 16), 256, 0, stream>>>(q, mbits, kb, vt, outp, attn);
}

// Round 10
// 239.033 us; speedup vs baseline: 1.2680x; 1.1655x over previous
//
#include <hip/hip_runtime.h>
#include <hip/hip_bf16.h>

#define BB 8
#define SQ 2048
#define SK 2048
#define DD 128
// 1/sqrt(128) * log2(e): K pre-scaled so QK acc feeds exp2 directly
#define KSCALE 0.12751649736401815f

using s16x8 = __attribute__((ext_vector_type(8))) short;
using s16x4 = __attribute__((ext_vector_type(4))) short;
using f32x4 = __attribute__((ext_vector_type(4))) float;

__device__ __forceinline__ unsigned short f2bf(float f) {
  union { float f; unsigned u; } v; v.f = f;
  unsigned r = v.u + 0x7FFFu + ((v.u >> 16) & 1u);
  return (unsigned short)(r >> 16);
}
__device__ __forceinline__ float bf2f(unsigned short h) {
  union { unsigned u; float f; } v; v.u = ((unsigned)h) << 16; return v.f;
}
__device__ __forceinline__ void bar_lds() {
  asm volatile("s_waitcnt lgkmcnt(0)" ::: "memory");
  __builtin_amdgcn_s_barrier();
}

// Merged prep: [0,1024) K->bf16*KSCALE; [1024,1280) V->bf16 V^T; [1280,5376) maskpack
__global__ __launch_bounds__(256) void prep_all(
    const float* __restrict__ k, const float* __restrict__ v,
    const int* __restrict__ m, unsigned short* __restrict__ kb,
    unsigned short* __restrict__ vt, unsigned long long* __restrict__ mb) {
  const int bid = blockIdx.x;
  const int tid = threadIdx.x;
  if (bid < 1024) {            // ---- K scale+convert ----
    const size_t i = ((size_t)bid * 256 + tid) * 8;
    const float4 a = *(const float4*)(k + i);
    const float4 c = *(const float4*)(k + i + 4);
    ushort4 o0, o1;
    o0.x = f2bf(a.x * KSCALE); o0.y = f2bf(a.y * KSCALE);
    o0.z = f2bf(a.z * KSCALE); o0.w = f2bf(a.w * KSCALE);
    o1.x = f2bf(c.x * KSCALE); o1.y = f2bf(c.y * KSCALE);
    o1.z = f2bf(c.z * KSCALE); o1.w = f2bf(c.w * KSCALE);
    *(ushort4*)(kb + i) = o0;
    *(ushort4*)(kb + i + 4) = o1;
  } else if (bid < 1280) {     // ---- V transpose ----
    constexpr int TS = 132;
    __shared__ __align__(16) unsigned short tile[64 * TS];
    const int vb = bid - 1024;
    const int b  = vb >> 5;
    const int k0 = (vb & 31) << 6;
#pragma unroll
    for (int p = 0; p < 8; ++p) {
      const int row = p * 8 + (tid >> 5);
      const int c4  = (tid & 31) << 2;
      const float4 vv = *(const float4*)(v + ((size_t)(b * SK + k0 + row)) * DD + c4);
      ushort4 o; o.x = f2bf(vv.x); o.y = f2bf(vv.y); o.z = f2bf(vv.z); o.w = f2bf(vv.w);
      *(ushort4*)(&tile[row * TS + c4]) = o;
    }
    __syncthreads();
#pragma unroll
    for (int p = 0; p < 8; ++p) {
      const int u = p * 256 + tid;
      const int d  = u >> 4;
      const int kw = (u & 15) << 2;
      ushort4 o;
      o.x = tile[(kw + 0) * TS + d];
      o.y = tile[(kw + 1) * TS + d];
      o.z = tile[(kw + 2) * TS + d];
      o.w = tile[(kw + 3) * TS + d];
      *(ushort4*)(vt + ((size_t)(b * DD + d)) * SK + k0 + kw) = o;
    }
  } else {                     // ---- mask -> bits ----
    const int gw = ((bid - 1280) * 256 + tid) >> 6;  // global row
    const int lane = tid & 63;
    const int* rp = m + (size_t)gw * SK;
    unsigned long long* wp = mb + (size_t)gw * (SK / 64);
#pragma unroll 4
    for (int i = 0; i < 32; ++i) {
      const int mv = rp[i * 64 + lane];
      const unsigned long long bal = __ballot(mv != 0);
      if (lane == 0) wp[i] = bal;
    }
  }
}

// Fused attention: 1024 blocks (4/CU) x 512 thr (8 waves), 16 q-rows/block.
// <=64 VGPR forced -> 8 waves/SIMD -> 32 waves/CU. 2-pass no-max softmax with
// QK recompute; K pre-scaled so e = exp2(acc).
#define BMSR 264  // mask-bit row stride (bytes)
#define LDP  136  // p_lds row stride (ushorts)
#define OBS  132  // obuf row stride (floats)

__global__ __launch_bounds__(512, 8) void fused_attn(
    const float* __restrict__ q, const unsigned long long* __restrict__ mb,
    const unsigned short* __restrict__ kb, const unsigned short* __restrict__ vt,
    float* __restrict__ outp, float* __restrict__ attn) {
  __shared__ unsigned char bm[16 * BMSR];                  // 4,224 B
  __shared__ __align__(16) unsigned short p_lds[2][16][LDP]; // 8,704 B
  __shared__ float obuf[16 * OBS];                         // 8,448 B
  __shared__ float redl[8][16];                            //   512 B
  __shared__ float il_s[16];                               //    64 B

  const int tid = threadIdx.x;
  const int bid = blockIdx.x;
  // 1024 blocks = 8 XCD x 128 (bijective)
  const int swz = ((bid & 7) << 7) + (bid >> 3);
  const int b  = swz >> 7;
  const int q0 = (swz & 127) << 4;   // 16 q-rows
  const int lane = tid & 63;
  const int w    = tid >> 6;         // wave 0..7
  const int lrow = lane & 15;
  const int lk   = lane >> 4;
  const int rowb = lk << 2;
  const int colw = (w << 4) + lrow;  // wave's k-col within 128-chunk / d-col for PV

  // stage mask bits: 16 rows x 32 u64 = 512 words, one per thread
  {
    const unsigned long long* src = mb + (size_t)(b * SQ + q0) * (SK / 64);
    const int row = tid >> 5, wd = tid & 31;
    *(unsigned long long*)&bm[row * BMSR + (wd << 3)] = src[row * 32 + wd];
  }

  // Q A-fragments (16 rows x 128 d)
  s16x8 af[4];
#pragma unroll
  for (int ks = 0; ks < 4; ++ks) {
    const float* qp = q + ((size_t)(b * SQ + q0 + lrow)) * DD + ks * 32 + lk * 8;
    const float4 a0 = *(const float4*)qp;
    const float4 a1 = *(const float4*)(qp + 4);
    s16x8 x;
    x[0] = (short)f2bf(a0.x); x[1] = (short)f2bf(a0.y); x[2] = (short)f2bf(a0.z); x[3] = (short)f2bf(a0.w);
    x[4] = (short)f2bf(a1.x); x[5] = (short)f2bf(a1.y); x[6] = (short)f2bf(a1.z); x[7] = (short)f2bf(a1.w);
    af[ks] = x;
  }

  // K base: lane's row = t*128 + colw, d-offset lk*8
  const unsigned short* kfp = kb + ((size_t)(b * SK + colw)) * DD + lk * 8;
  const int byb = (colw >> 3);      // byte within 16-byte group of a 128-chunk
  const int bit = colw & 7;

  __syncthreads();  // bm ready

  // ---- pass 1: l[row] = sum_k exp2(acc) ----
  float ls[4] = {0.f, 0.f, 0.f, 0.f};
#pragma unroll 1
  for (int t = 0; t < 16; ++t) {
    const unsigned short* kp = kfp + (size_t)t * (128 * DD);
    f32x4 acc = {0.f, 0.f, 0.f, 0.f};
    s16x8 k0 = *(const s16x8*)(kp);
    s16x8 k1 = *(const s16x8*)(kp + 32);
    acc = __builtin_amdgcn_mfma_f32_16x16x32_bf16(af[0], k0, acc, 0, 0, 0);
    acc = __builtin_amdgcn_mfma_f32_16x16x32_bf16(af[1], k1, acc, 0, 0, 0);
    k0 = *(const s16x8*)(kp + 64);
    k1 = *(const s16x8*)(kp + 96);
    acc = __builtin_amdgcn_mfma_f32_16x16x32_bf16(af[2], k0, acc, 0, 0, 0);
    acc = __builtin_amdgcn_mfma_f32_16x16x32_bf16(af[3], k1, acc, 0, 0, 0);
    const int bb0 = (t << 4) + byb;
#pragma unroll
    for (int r = 0; r < 4; ++r) {
      const int live = (bm[(rowb + r) * BMSR + bb0] >> bit) & 1;
      const float e = exp2f(acc[r]);
      ls[r] += live ? e : 0.0f;
    }
  }

  // ---- l reduce: shfl over 16-lane col group + cross-wave LDS ----
#pragma unroll
  for (int r = 0; r < 4; ++r) {
    float l = ls[r];
#pragma unroll
    for (int d = 1; d < 16; d <<= 1) l += __shfl_xor(l, d);
    ls[r] = l;
  }
  if (lrow == 0) {
#pragma unroll
    for (int r = 0; r < 4; ++r) redl[w][rowb + r] = ls[r];
  }
  __syncthreads();
  if (tid < 16) {
    float l = 0.f;
#pragma unroll
    for (int ww = 0; ww < 8; ++ww) l += redl[ww][tid];
    il_s[tid] = 1.0f / l;
  }
  __syncthreads();
  float il[4];
#pragma unroll
  for (int r = 0; r < 4; ++r) il[r] = il_s[rowb + r];

  // ---- pass 2: recompute -> p -> p_lds -> attn store + PV ----
  f32x4 o = {0.f, 0.f, 0.f, 0.f};
  const unsigned short* vfp = vt + ((size_t)(b * DD + colw)) * SK + lk * 8;
  const int arow = tid >> 5;          // 0..15
  const int acg  = (tid & 31) << 2;   // 0..124
  float* abase = attn + ((size_t)(b * SQ + q0 + arow)) * SK + acg;

#pragma unroll 2
  for (int t = 0; t < 16; ++t) {
    const int buf = t & 1;
    const unsigned short* kp = kfp + (size_t)t * (128 * DD);
    f32x4 acc = {0.f, 0.f, 0.f, 0.f};
    s16x8 k0 = *(const s16x8*)(kp);
    s16x8 k1 = *(const s16x8*)(kp + 32);
    acc = __builtin_amdgcn_mfma_f32_16x16x32_bf16(af[0], k0, acc, 0, 0, 0);
    acc = __builtin_amdgcn_mfma_f32_16x16x32_bf16(af[1], k1, acc, 0, 0, 0);
    k0 = *(const s16x8*)(kp + 64);
    k1 = *(const s16x8*)(kp + 96);
    acc = __builtin_amdgcn_mfma_f32_16x16x32_bf16(af[2], k0, acc, 0, 0, 0);
    acc = __builtin_amdgcn_mfma_f32_16x16x32_bf16(af[3], k1, acc, 0, 0, 0);
    const int bb0 = (t << 4) + byb;
#pragma unroll
    for (int r = 0; r < 4; ++r) {
      const int live = (bm[(rowb + r) * BMSR + bb0] >> bit) & 1;
      const float e = exp2f(acc[r]) * il[r];
      p_lds[buf][rowb + r][colw] = f2bf(live ? e : 0.0f);
    }
    bar_lds();  // publish p tile (global loads stay in flight)
    // attn store: 4 fp32/thread, 32 lanes = 512B contiguous
    {
      const s16x4 pr = *(const s16x4*)(&p_lds[buf][arow][acg]);
      float4 g;
      g.x = bf2f((unsigned short)pr[0]); g.y = bf2f((unsigned short)pr[1]);
      g.z = bf2f((unsigned short)pr[2]); g.w = bf2f((unsigned short)pr[3]);
      *(float4*)(abase + (t << 7)) = g;
    }
    // PV: o[16 rows x d=colw] += P[16x128] * V^T[colw][128]
    __builtin_amdgcn_s_setprio(1);
#pragma unroll
    for (int ks = 0; ks < 4; ++ks) {
      const s16x8 pa = *(const s16x8*)(&p_lds[buf][lrow][ks * 32 + lk * 8]);
      const s16x8 vf = *(const s16x8*)(vfp + (t << 7) + ks * 32);
      o = __builtin_amdgcn_mfma_f32_16x16x32_bf16(pa, vf, o, 0, 0, 0);
    }
    __builtin_amdgcn_s_setprio(0);
  }

  // ---- epilogue: bounce O through LDS for coalesced out stores ----
  bar_lds();  // all p_lds reads drained; reuse-safe
#pragma unroll
  for (int r = 0; r < 4; ++r)
    obuf[(rowb + r) * OBS + colw] = o[r];
  __syncthreads();
  {
    const int orow = tid >> 5;
    const int ocg  = (tid & 31) << 2;
    const float* ob = &obuf[orow * OBS + ocg];
    float4 u;
    u.x = ob[0]; u.y = ob[1]; u.z = ob[2]; u.w = ob[3];
    *(float4*)(outp + ((size_t)(b * SQ + q0 + orow)) * DD + ocg) = u;
  }
}

extern "C" void kernel_launch(void* const* d_in, const int* in_sizes, int n_in,
                              void* d_out, int out_size, void* d_ws, size_t ws_size,
                              hipStream_t stream) {
  const float* q = (const float*)d_in[0];
  const float* k = (const float*)d_in[1];
  const float* v = (const float*)d_in[2];
  const int* mask = (const int*)d_in[3];
  float* outp = (float*)d_out;
  float* attn = outp + (size_t)BB * SQ * DD;

  unsigned short* kb = (unsigned short*)d_ws;                       // 8 MB
  unsigned short* vt = kb + (size_t)BB * SK * DD;                   // 8 MB
  unsigned long long* mbits = (unsigned long long*)(vt + (size_t)BB * SK * DD);  // 4 MB

  prep_all<<<1024 + 256 + 4096, 256, 0, stream>>>(k, v, mask, kb, vt, mbits);
  fused_attn<<<BB * (SQ / 16), 512, 0, stream>>>(q, mbits, kb, vt, outp, attn);
}